// Round 1
// baseline (216.176 us; speedup 1.0000x reference)
//
#include <hip/hip_runtime.h>
#include <hip/hip_bf16.h>

// Problem constants (B=1 folded out)
constexpr int T = 8;     // frames
constexpr int C = 128;   // input channels
constexpr int N = 4096;  // H*W positions
constexpr int F = 64;    // feature dim

typedef __bf16 bf16x8 __attribute__((ext_vector_type(8)));
typedef __bf16 bf16x4 __attribute__((ext_vector_type(4)));
typedef __bf16 bf16x2 __attribute__((ext_vector_type(2)));
typedef float  f32x4  __attribute__((ext_vector_type(4)));
typedef float  f32x16 __attribute__((ext_vector_type(16)));

// ---------------------------------------------------------------------------
// Kernel 0: convert W1/W2/W3 (fp32 [F][C]) to bf16, packed [3][F][C]
// ---------------------------------------------------------------------------
__global__ __launch_bounds__(256) void prep_w_kernel(
    const float* __restrict__ W1, const float* __restrict__ W2,
    const float* __restrict__ W3, __bf16* __restrict__ Wb)
{
    int i = blockIdx.x * 256 + threadIdx.x;   // grid covers 3*F*C = 24576
    const float* Ws[3] = {W1, W2, W3};
    int p = i >> 13, r = i & 8191;
    Wb[i] = (__bf16)Ws[p][r];
}

// ---------------------------------------------------------------------------
// Kernel 1: projections (unchanged — measured correct).
//   Q = x1ᵀW1ᵀ+b1  -> bf16 [t][n][F]
//   K = x2ᵀW2ᵀ+b2  -> bf16 [t][n][F]
//   G = x1ᵀW3ᵀ+b3  -> bf16 [t][f][N]  (transposed: PV A-operand reads along keys)
// ---------------------------------------------------------------------------
__global__ __launch_bounds__(256) void proj_kernel(
    const float* __restrict__ x1, const float* __restrict__ x2,
    const __bf16* __restrict__ Wb,
    const float* __restrict__ b1, const float* __restrict__ b2,
    const float* __restrict__ b3,
    __bf16* __restrict__ Qb, __bf16* __restrict__ Kb, __bf16* __restrict__ Gw)
{
    const int t  = blockIdx.x >> 6;
    const int nb = blockIdx.x & 63;
    const int n0 = nb * 64;

    constexpr int XS = C + 8;         // 136 bf16 -> 272B rows (16B aligned)
    __shared__ __bf16 Xt1[64 * XS];   // X1ᵀ tile: [n_local][c]
    __shared__ __bf16 Xt2[64 * XS];

    const int tid = threadIdx.x;
#pragma unroll
    for (int rep = 0; rep < 32; ++rep) {
        int idx = rep * 256 + tid;
        int c = idx >> 6, nl = idx & 63;
        size_t goff = ((size_t)t * C + c) * (size_t)N + n0 + nl;
        Xt1[nl * XS + c] = (__bf16)x1[goff];
        Xt2[nl * XS + c] = (__bf16)x2[goff];
    }
    __syncthreads();

    const int wave = tid >> 6, lane = tid & 63;
    const int quad = lane >> 4, l16 = lane & 15;

    bf16x8 a1[4], a2[4];
#pragma unroll
    for (int cc = 0; cc < 4; ++cc) {
        a1[cc] = *(const bf16x8*)&Xt1[(wave * 16 + l16) * XS + cc * 32 + quad * 8];
        a2[cc] = *(const bf16x8*)&Xt2[(wave * 16 + l16) * XS + cc * 32 + quad * 8];
    }

    // ---- Q and K: D[m=n][n'=f] ----
#pragma unroll
    for (int p = 0; p < 2; ++p) {
        const __bf16* W    = Wb + (size_t)p * F * C;
        const float*  bias = p ? b2 : b1;
        __bf16*       O    = p ? Kb : Qb;

        f32x4 acc[4];
#pragma unroll
        for (int ft = 0; ft < 4; ++ft) acc[ft] = (f32x4){0.f, 0.f, 0.f, 0.f};
#pragma unroll
        for (int cc = 0; cc < 4; ++cc) {
#pragma unroll
            for (int ft = 0; ft < 4; ++ft) {
                bf16x8 b = *(const bf16x8*)&W[(ft * 16 + l16) * C + cc * 32 + quad * 8];
                bf16x8 a = p ? a2[cc] : a1[cc];
                acc[ft] = __builtin_amdgcn_mfma_f32_16x16x32_bf16(a, b, acc[ft], 0, 0, 0);
            }
        }
#pragma unroll
        for (int ft = 0; ft < 4; ++ft) {
            int f = ft * 16 + l16;
            float bv = bias[f];
#pragma unroll
            for (int r = 0; r < 4; ++r) {
                int n = n0 + wave * 16 + quad * 4 + r;
                O[((size_t)t * N + n) * F + f] = (__bf16)(acc[ft][r] + bv);
            }
        }
    }

    // ---- G transposed: D[m=f][n'=npos] ----
    {
        const __bf16* W3b = Wb + (size_t)2 * F * C;
        bf16x8 wa[4];
#pragma unroll
        for (int cc = 0; cc < 4; ++cc)
            wa[cc] = *(const bf16x8*)&W3b[(wave * 16 + l16) * C + cc * 32 + quad * 8];

        f32x4 acc[4];
#pragma unroll
        for (int nt = 0; nt < 4; ++nt) acc[nt] = (f32x4){0.f, 0.f, 0.f, 0.f};
#pragma unroll
        for (int cc = 0; cc < 4; ++cc) {
#pragma unroll
            for (int nt = 0; nt < 4; ++nt) {
                bf16x8 b = *(const bf16x8*)&Xt1[(nt * 16 + l16) * XS + cc * 32 + quad * 8];
                acc[nt] = __builtin_amdgcn_mfma_f32_16x16x32_bf16(wa[cc], b, acc[nt], 0, 0, 0);
            }
        }
#pragma unroll
        for (int nt = 0; nt < 4; ++nt) {
#pragma unroll
            for (int r = 0; r < 4; ++r) {
                int f = wave * 16 + quad * 4 + r;
                int n = n0 + nt * 16 + l16;
                Gw[((size_t)t * F + f) * (size_t)N + n] = (__bf16)(acc[nt][r] + b3[f]);
            }
        }
    }
}

// ---------------------------------------------------------------------------
// Kernel 2: O[t][f][q] = sum_key relu(Q[q]·K[key]) * G[key][f]
//
// Zero-LDS main loop. Block = 512 threads = 8 waves = (2 q-halves × 4 key
// slices) over a 128-q strip of one frame. Per wave: 64 q, 1024 keys, all
// operands as register fragments straight from L2 (frame working set 1.5 MB,
// pinned per-XCD via t = blockIdx&7). 32x32x16 MFMA; Sᵀ = relu(K·Qᵀ) stays
// in registers: relu+pack to bf16, v_permlane32_swap redistributes into the
// PV B-fragment layout (keys {4m..} live 4-apart across lane halves; the
// P0↔P2 / P1↔P3 swaps assemble 8 consecutive keys per lane half).
// K double-buffered in regs, G issued one phase early. Cross-wave combine
// once at the end via LDS ds_add_f32, then plain coalesced stores (no global
// atomics, no zero kernel).
// ---------------------------------------------------------------------------

#define PACK_PS(SACC, PS0, PS1)                                              \
    {                                                                        \
        unsigned P[8];                                                       \
        _Pragma("unroll")                                                    \
        for (int m = 0; m < 8; ++m) {                                        \
            union { bf16x2 h; unsigned u; } pk_;                             \
            pk_.h[0] = (__bf16)fmaxf(SACC[2 * m], 0.f);                      \
            pk_.h[1] = (__bf16)fmaxf(SACC[2 * m + 1], 0.f);                  \
            P[m] = pk_.u;                                                    \
        }                                                                    \
        asm("v_permlane32_swap_b32 %0, %1" : "+v"(P[0]), "+v"(P[2]));        \
        asm("v_permlane32_swap_b32 %0, %1" : "+v"(P[1]), "+v"(P[3]));        \
        asm("v_permlane32_swap_b32 %0, %1" : "+v"(P[4]), "+v"(P[6]));        \
        asm("v_permlane32_swap_b32 %0, %1" : "+v"(P[5]), "+v"(P[7]));        \
        union { unsigned u[4]; bf16x8 v; } lo_, hi_;                         \
        lo_.u[0] = P[0]; lo_.u[1] = P[1]; lo_.u[2] = P[2]; lo_.u[3] = P[3];  \
        hi_.u[0] = P[4]; hi_.u[1] = P[5]; hi_.u[2] = P[6]; hi_.u[3] = P[7];  \
        PS0 = lo_.v; PS1 = hi_.v;                                            \
    }

// One 64-key step. KF: current K frags; KN: prefetch target (other buffer).
// Order: issue G(kb) -> S(qg0) [last KF wait] -> pack -> prefetch K(kbn)
//        -> PV(qg0) [G wait lands here, ~250cy after issue]
//        -> S(qg1) -> pack -> PV(qg1). KF stays live through S(qg1).
#define ATTN_STEP(KF, KN)                                                    \
    {                                                                        \
        _Pragma("unroll")                                                    \
        for (int c = 0; c < 4; ++c)                                          \
            _Pragma("unroll")                                                \
            for (int ft = 0; ft < 2; ++ft)                                   \
                gf[c][ft] = *(const bf16x8*)(gptr + (size_t)ft * 32 * N + kb + c * 16); \
        bf16x8 ps[4];                                                        \
        _Pragma("unroll")                                                    \
        for (int kt = 0; kt < 2; ++kt) {                                     \
            f32x16 s;                                                        \
            _Pragma("unroll")                                                \
            for (int r = 0; r < 16; ++r) s[r] = 0.f;                         \
            _Pragma("unroll")                                                \
            for (int fc = 0; fc < 4; ++fc)                                   \
                s = __builtin_amdgcn_mfma_f32_32x32x16_bf16(KF[kt][fc], qf[0][fc], s, 0, 0, 0); \
            PACK_PS(s, ps[kt * 2], ps[kt * 2 + 1])                           \
        }                                                                    \
        _Pragma("unroll")                                                    \
        for (int kt = 0; kt < 2; ++kt)                                       \
            _Pragma("unroll")                                                \
            for (int fc = 0; fc < 4; ++fc)                                   \
                KN[kt][fc] = *(const bf16x8*)(kptr + (size_t)(kbn + kt * 32) * F + fc * 16); \
        _Pragma("unroll")                                                    \
        for (int c = 0; c < 4; ++c)                                          \
            _Pragma("unroll")                                                \
            for (int ft = 0; ft < 2; ++ft)                                   \
                oacc[0][ft] = __builtin_amdgcn_mfma_f32_32x32x16_bf16(gf[c][ft], ps[c], oacc[0][ft], 0, 0, 0); \
        _Pragma("unroll")                                                    \
        for (int kt = 0; kt < 2; ++kt) {                                     \
            f32x16 s;                                                        \
            _Pragma("unroll")                                                \
            for (int r = 0; r < 16; ++r) s[r] = 0.f;                         \
            _Pragma("unroll")                                                \
            for (int fc = 0; fc < 4; ++fc)                                   \
                s = __builtin_amdgcn_mfma_f32_32x32x16_bf16(KF[kt][fc], qf[1][fc], s, 0, 0, 0); \
            PACK_PS(s, ps[kt * 2], ps[kt * 2 + 1])                           \
        }                                                                    \
        _Pragma("unroll")                                                    \
        for (int c = 0; c < 4; ++c)                                          \
            _Pragma("unroll")                                                \
            for (int ft = 0; ft < 2; ++ft)                                   \
                oacc[1][ft] = __builtin_amdgcn_mfma_f32_32x32x16_bf16(gf[c][ft], ps[c], oacc[1][ft], 0, 0, 0); \
        kb  = kbn;                                                           \
        kbn = (kbn + 64 < kw0 + N / 4) ? kbn + 64 : kw0;                     \
    }

__global__ __launch_bounds__(512, 2) void attn_kernel(
    const __bf16* __restrict__ Qb, const __bf16* __restrict__ Kb,
    const __bf16* __restrict__ Gw, float* __restrict__ out)
{
    const int t  = blockIdx.x & 7;    // frame -> XCD-aligned (b%8 round-robin)
    const int qb = blockIdx.x >> 3;   // 32 strips of 128 q
    const int q0 = qb * 128;

    const int tid  = threadIdx.x;
    const int wave = tid >> 6, lane = tid & 63;
    const int m32  = lane & 31, hi = lane >> 5;
    const int qh   = wave & 1;        // q-half (64 q) within the strip
    const int ksl  = wave >> 1;       // key slice: 1024 keys per wave
    const int kw0  = ksl * (N / 4);

    __shared__ __align__(16) float red[2][64][68];  // [qh][f][q] f32, padded

    // Q fragments: B[k=f][n=q]; lane holds Q[q0+qh*64+qg*32+m32][fc*16+hi*8+j]
    bf16x8 qf[2][4];
    {
        const __bf16* qptr = Qb + ((size_t)t * N + q0 + qh * 64 + m32) * F + hi * 8;
#pragma unroll
        for (int qg = 0; qg < 2; ++qg)
#pragma unroll
            for (int fc = 0; fc < 4; ++fc)
                qf[qg][fc] = *(const bf16x8*)(qptr + qg * 32 * F + fc * 16);
    }

    f32x16 oacc[2][2];   // [qg][f-tile]; D: col=q=m32, row=(r&3)+8*(r>>2)+4*hi
#pragma unroll
    for (int qg = 0; qg < 2; ++qg)
#pragma unroll
        for (int ft = 0; ft < 2; ++ft)
#pragma unroll
            for (int r = 0; r < 16; ++r) oacc[qg][ft][r] = 0.f;

    const __bf16* kptr = Kb + ((size_t)t * N + m32) * F + hi * 8;
    const __bf16* gptr = Gw + ((size_t)t * F + m32) * (size_t)N + hi * 8;

    bf16x8 kfA[2][4], kfB[2][4], gf[4][2];

    // prologue: K tile for first step
#pragma unroll
    for (int kt = 0; kt < 2; ++kt)
#pragma unroll
        for (int fc = 0; fc < 4; ++fc)
            kfA[kt][fc] = *(const bf16x8*)(kptr + (size_t)(kw0 + kt * 32) * F + fc * 16);

    int kb = kw0, kbn = kw0 + 64;

#pragma unroll 1
    for (int it = 0; it < 8; ++it) {
        ATTN_STEP(kfA, kfB)
        ATTN_STEP(kfB, kfA)
    }

    // ---- epilogue: cross-wave (key-slice) reduction in LDS, plain stores ----
#pragma unroll
    for (int i = 0; i < 17; ++i)                   // 17*512 == 2*64*68
        ((float*)red)[i * 512 + tid] = 0.f;
    __syncthreads();

    {
        float* buf = &red[qh][0][0];
#pragma unroll
        for (int qg = 0; qg < 2; ++qg)
#pragma unroll
            for (int ft = 0; ft < 2; ++ft)
#pragma unroll
                for (int r = 0; r < 16; ++r) {
                    int f = ft * 32 + (r & 3) + 8 * (r >> 2) + 4 * hi;
                    atomicAdd(&buf[f * 68 + qg * 32 + m32], oacc[qg][ft][r]);
                }
    }
    __syncthreads();

    {
        const int qh_t = tid >> 8;
        const int fr   = (tid >> 2) & 63;
        const int qq   = tid & 3;
        const float* rp = &red[qh_t][fr][qq * 16];
        float* op = out + ((size_t)t * F + fr) * (size_t)N + q0 + qh_t * 64 + qq * 16;
#pragma unroll
        for (int j = 0; j < 4; ++j)
            *(f32x4*)(op + 4 * j) = *(const f32x4*)(rp + 4 * j);
    }
}

// ---------------------------------------------------------------------------
extern "C" void kernel_launch(void* const* d_in, const int* in_sizes, int n_in,
                              void* d_out, int out_size, void* d_ws, size_t ws_size,
                              hipStream_t stream) {
    const float* x1 = (const float*)d_in[0];
    const float* x2 = (const float*)d_in[1];
    const float* W1 = (const float*)d_in[2];
    const float* b1 = (const float*)d_in[3];
    const float* W2 = (const float*)d_in[4];
    const float* b2 = (const float*)d_in[5];
    const float* W3 = (const float*)d_in[6];
    const float* b3 = (const float*)d_in[7];
    float* out = (float*)d_out;

    __bf16* Qb = (__bf16*)d_ws;
    __bf16* Kb = Qb + (size_t)T * N * F;
    __bf16* Gw = Kb + (size_t)T * N * F;
    __bf16* Wb = Gw + (size_t)T * N * F;

    prep_w_kernel<<<dim3(3 * F * C / 256), dim3(256), 0, stream>>>(W1, W2, W3, Wb);
    proj_kernel<<<dim3(T * (N / 64)), dim3(256), 0, stream>>>(
        x1, x2, Wb, b1, b2, b3, Qb, Kb, Gw);
    attn_kernel<<<dim3(T * (N / 128)), dim3(512), 0, stream>>>(Qb, Kb, Gw, out);
}

// Round 2
// 156.454 us; speedup vs baseline: 1.3817x; 1.3817x over previous
//
#include <hip/hip_runtime.h>
#include <hip/hip_bf16.h>

// Problem constants (B=1 folded out)
constexpr int T = 8;     // frames
constexpr int C = 128;   // input channels
constexpr int N = 4096;  // H*W positions
constexpr int F = 64;    // feature dim

typedef __bf16 bf16x8 __attribute__((ext_vector_type(8)));
typedef __bf16 bf16x4 __attribute__((ext_vector_type(4)));
typedef float  f32x4  __attribute__((ext_vector_type(4)));

// ---------------------------------------------------------------------------
// Kernel 0: convert W1/W2/W3 (fp32 [F][C]) to bf16, packed [3][F][C]
// (branchy pointer select instead of indexed stack array -> no scratch)
// ---------------------------------------------------------------------------
__global__ __launch_bounds__(256) void prep_w_kernel(
    const float* __restrict__ W1, const float* __restrict__ W2,
    const float* __restrict__ W3, __bf16* __restrict__ Wb)
{
    int i = blockIdx.x * 256 + threadIdx.x;   // grid covers 3*F*C = 24576
    int p = i >> 13, r = i & 8191;
    const float* W = (p == 0) ? W1 : (p == 1) ? W2 : W3;
    Wb[i] = (__bf16)W[r];
}

// ---------------------------------------------------------------------------
// Kernel 0b: zero d_out (poisoned before every launch; attn accumulates with
// atomics)
// ---------------------------------------------------------------------------
__global__ __launch_bounds__(256) void zero_out_kernel(float* __restrict__ out)
{
    int i = blockIdx.x * 256 + threadIdx.x;   // grid covers T*F*N/4 float4s
    ((f32x4*)out)[i] = (f32x4){0.f, 0.f, 0.f, 0.f};
}

// ---------------------------------------------------------------------------
// Kernel 1: projections, vectorized rewrite.
//   Staging: f32x4 global loads (256B/16-lane segments), 4x4 in-register
//   transpose, b64 LDS writes -> X^T tiles [n][c] in LDS.
//   GEMM orientations chosen so every lane's 4 accumulator rows are
//   contiguous in the STORED dimension -> b64 stores:
//     Q,K: D[m=f][n'=n] = W · X^T   (A = W-frag, B = x-frag) -> [n][F], b64 over f
//     G:   D[m=n][n'=f] = X^T · W3  (A = x-frag, B = W3-frag) -> [f][N], b64 over n
//   A/B per-lane fragment layouts are identical (8 k-contiguous elems, lane
//   l16 = m-or-n' index, quad = k-chunk), so x-frags are shared by all three.
// ---------------------------------------------------------------------------
__global__ __launch_bounds__(256) void proj_kernel(
    const float* __restrict__ x1, const float* __restrict__ x2,
    const __bf16* __restrict__ Wb,
    const float* __restrict__ b1, const float* __restrict__ b2,
    const float* __restrict__ b3,
    __bf16* __restrict__ Qb, __bf16* __restrict__ Kb, __bf16* __restrict__ Gw)
{
    const int t  = blockIdx.x >> 6;
    const int nb = blockIdx.x & 63;
    const int n0 = nb * 64;

    constexpr int XS = 136;           // 272B rows (16B aligned)
    __shared__ __bf16 Xt1[64 * XS];   // X1^T tile: [n_local][c]
    __shared__ __bf16 Xt2[64 * XS];

    const int tid = threadIdx.x;
    const int ng  = tid & 15;         // n-block: n = ng*4 + j
    const int cgi = tid >> 4;         // c-group: c = cgi*4 (+64 per pass)

#pragma unroll
    for (int pass = 0; pass < 2; ++pass) {
        const int c0 = cgi * 4 + pass * 64;
        const size_t base = ((size_t)t * C + c0) * (size_t)N + n0 + ng * 4;
        f32x4 v1[4], v2[4];
#pragma unroll
        for (int i = 0; i < 4; ++i) {
            v1[i] = *(const f32x4*)&x1[base + (size_t)i * N];
            v2[i] = *(const f32x4*)&x2[base + (size_t)i * N];
        }
#pragma unroll
        for (int j = 0; j < 4; ++j) {
            bf16x4 o1, o2;
#pragma unroll
            for (int i = 0; i < 4; ++i) {
                o1[i] = (__bf16)v1[i][j];
                o2[i] = (__bf16)v2[i][j];
            }
            *(bf16x4*)&Xt1[(ng * 4 + j) * XS + c0] = o1;
            *(bf16x4*)&Xt2[(ng * 4 + j) * XS + c0] = o2;
        }
    }
    __syncthreads();

    const int wave = tid >> 6, lane = tid & 63;
    const int quad = lane >> 4, l16 = lane & 15;

    // X^T fragments: lane holds 8 c-contiguous elems of row n = wave*16+l16
    bf16x8 a1[4], a2[4];
#pragma unroll
    for (int cc = 0; cc < 4; ++cc) {
        a1[cc] = *(const bf16x8*)&Xt1[(wave * 16 + l16) * XS + cc * 32 + quad * 8];
        a2[cc] = *(const bf16x8*)&Xt2[(wave * 16 + l16) * XS + cc * 32 + quad * 8];
    }

    // ---- Q and K: D[m=f][n'=n] = W · X^T ----
#pragma unroll
    for (int p = 0; p < 2; ++p) {
        const __bf16* W    = Wb + (size_t)p * F * C;
        const float*  bias = p ? b2 : b1;
        __bf16*       O    = p ? Kb : Qb;

        f32x4 acc[4];
#pragma unroll
        for (int ft = 0; ft < 4; ++ft) acc[ft] = (f32x4){0.f, 0.f, 0.f, 0.f};
#pragma unroll
        for (int cc = 0; cc < 4; ++cc) {
#pragma unroll
            for (int ft = 0; ft < 4; ++ft) {
                bf16x8 wf = *(const bf16x8*)&W[(ft * 16 + l16) * C + cc * 32 + quad * 8];
                bf16x8 xf = p ? a2[cc] : a1[cc];
                acc[ft] = __builtin_amdgcn_mfma_f32_16x16x32_bf16(wf, xf, acc[ft], 0, 0, 0);
            }
        }
        // D: col = n = wave*16+l16, row = f = ft*16 + quad*4 + r (contiguous!)
        const int n = n0 + wave * 16 + l16;
#pragma unroll
        for (int ft = 0; ft < 4; ++ft) {
            const int f0 = ft * 16 + quad * 4;
            f32x4 bv = *(const f32x4*)&bias[f0];
            bf16x4 o;
#pragma unroll
            for (int r = 0; r < 4; ++r) o[r] = (__bf16)(acc[ft][r] + bv[r]);
            *(bf16x4*)&O[((size_t)t * N + n) * F + f0] = o;
        }
    }

    // ---- G: D[m=n][n'=f] = X^T · W3 ----
    {
        const __bf16* W3b = Wb + (size_t)2 * F * C;
        f32x4 acc[4];
#pragma unroll
        for (int ft = 0; ft < 4; ++ft) acc[ft] = (f32x4){0.f, 0.f, 0.f, 0.f};
#pragma unroll
        for (int cc = 0; cc < 4; ++cc) {
#pragma unroll
            for (int ft = 0; ft < 4; ++ft) {
                bf16x8 wf = *(const bf16x8*)&W3b[(ft * 16 + l16) * C + cc * 32 + quad * 8];
                acc[ft] = __builtin_amdgcn_mfma_f32_16x16x32_bf16(a1[cc], wf, acc[ft], 0, 0, 0);
            }
        }
        // D: col = f = ft*16+l16, row = n = wave*16 + quad*4 + r (contiguous!)
        const int nr0 = n0 + wave * 16 + quad * 4;
#pragma unroll
        for (int ft = 0; ft < 4; ++ft) {
            const int f = ft * 16 + l16;
            const float bv = b3[f];
            bf16x4 o;
#pragma unroll
            for (int r = 0; r < 4; ++r) o[r] = (__bf16)(acc[ft][r] + bv);
            *(bf16x4*)&Gw[((size_t)t * F + f) * (size_t)N + nr0] = o;
        }
    }
}

// ---------------------------------------------------------------------------
// Kernel 2: O[t][f][q] += sum_key relu(Q[q]·K[key]) * G[key][f]
// Reverted to the verified round-0 structure (LDS-staged, Sᵀ via b64 Sb
// writes, register-prefetched next tile). Only change: KSPLIT 2 -> 4 for
// 4 blocks/CU (16 waves/CU) latency hiding.
// ---------------------------------------------------------------------------
constexpr int KSPLIT = 4;

__global__ __launch_bounds__(256) void attn_kernel(
    const __bf16* __restrict__ Qb, const __bf16* __restrict__ Kb,
    const __bf16* __restrict__ Gw, float* __restrict__ out)
{
    const int ks = blockIdx.x & (KSPLIT - 1);
    const int qb = (blockIdx.x / KSPLIT) & 31;   // N/128 = 32 q-blocks
    const int t  = blockIdx.x / (KSPLIT * 32);
    const int q0 = qb * 128;

    constexpr int KS = 72;              // bf16 stride (144B rows)
    __shared__ __bf16 Kt[64 * KS];      // K tile [key][f]
    __shared__ __bf16 Gt[64 * KS];      // G tile [f][key]
    __shared__ __bf16 Sb[128 * KS];     // Sᵀ-written, read as S [q][key]

    const int tid = threadIdx.x, wave = tid >> 6, lane = tid & 63;
    const int quad = lane >> 4, l16 = lane & 15;

    // Q B-frags: B[n=q][k=f], q = q0 + wave*32 + qg*16 + l16
    bf16x8 qf[2][2];
#pragma unroll
    for (int qg = 0; qg < 2; ++qg) {
        const __bf16* qrow = &Qb[((size_t)t * N + q0 + wave * 32 + qg * 16 + l16) * F];
        qf[qg][0] = *(const bf16x8*)&qrow[quad * 8];
        qf[qg][1] = *(const bf16x8*)&qrow[32 + quad * 8];
    }

    f32x4 oacc[4][2];
#pragma unroll
    for (int ft = 0; ft < 4; ++ft)
#pragma unroll
        for (int qg = 0; qg < 2; ++qg) oacc[ft][qg] = (f32x4){0.f, 0.f, 0.f, 0.f};

    const int kb_lo = ks * (N / 64 / KSPLIT);
    const int kb_hi = kb_lo + (N / 64 / KSPLIT);

    // staging unit for this thread: u in {tid, tid+256}; r8 = u>>3, c8 = (u&7)*8
    const int r8a = tid >> 3,          c8a = (tid & 7) * 8;
    const int r8b = (tid + 256) >> 3,  c8b = c8a;

    // prefetch tile kb_lo into registers
    bf16x8 kv0, kv1, gv0, gv1;
    {
        const int k0 = kb_lo * 64;
        kv0 = *(const bf16x8*)&Kb[((size_t)t * N + k0 + r8a) * F + c8a];
        kv1 = *(const bf16x8*)&Kb[((size_t)t * N + k0 + r8b) * F + c8b];
        gv0 = *(const bf16x8*)&Gw[((size_t)t * F + r8a) * (size_t)N + k0 + c8a];
        gv1 = *(const bf16x8*)&Gw[((size_t)t * F + r8b) * (size_t)N + k0 + c8b];
    }

    for (int kb = kb_lo; kb < kb_hi; ++kb) {
        __syncthreads();   // previous tile's LDS reads done
        *(bf16x8*)&Kt[r8a * KS + c8a] = kv0;
        *(bf16x8*)&Kt[r8b * KS + c8b] = kv1;
        *(bf16x8*)&Gt[r8a * KS + c8a] = gv0;
        *(bf16x8*)&Gt[r8b * KS + c8b] = gv1;
        __syncthreads();

        if (kb + 1 < kb_hi) {   // prefetch next tile (overlaps with compute)
            const int k0 = (kb + 1) * 64;
            kv0 = *(const bf16x8*)&Kb[((size_t)t * N + k0 + r8a) * F + c8a];
            kv1 = *(const bf16x8*)&Kb[((size_t)t * N + k0 + r8b) * F + c8b];
            gv0 = *(const bf16x8*)&Gw[((size_t)t * F + r8a) * (size_t)N + k0 + c8a];
            gv1 = *(const bf16x8*)&Gw[((size_t)t * F + r8b) * (size_t)N + k0 + c8b];
        }

        // Sᵀ = relu(K·Qᵀ): D[m=key][n=q]; kfrag shared across both q-groups
#pragma unroll
        for (int nt = 0; nt < 4; ++nt) {
            bf16x8 k0f = *(const bf16x8*)&Kt[(nt * 16 + l16) * KS + quad * 8];
            bf16x8 k1f = *(const bf16x8*)&Kt[(nt * 16 + l16) * KS + 32 + quad * 8];
#pragma unroll
            for (int qg = 0; qg < 2; ++qg) {
                f32x4 s = (f32x4){0.f, 0.f, 0.f, 0.f};
                s = __builtin_amdgcn_mfma_f32_16x16x32_bf16(k0f, qf[qg][0], s, 0, 0, 0);
                s = __builtin_amdgcn_mfma_f32_16x16x32_bf16(k1f, qf[qg][1], s, 0, 0, 0);
                // D: col=q_local=l16, row=key=nt*16+quad*4+r -> 4 consecutive
                // keys at fixed q -> single b64 store into Sb[q][key]
                bf16x4 sp;
#pragma unroll
                for (int r = 0; r < 4; ++r) sp[r] = (__bf16)fmaxf(s[r], 0.f);
                *(bf16x4*)&Sb[(wave * 32 + qg * 16 + l16) * KS + nt * 16 + quad * 4] = sp;
            }
        }

        // PV: Oᵀ[f][q] — wave reads only its own 32 Sb rows (no barrier)
        bf16x8 sf[2][2];
#pragma unroll
        for (int qg = 0; qg < 2; ++qg) {
            const __bf16* srow = &Sb[(wave * 32 + qg * 16 + l16) * KS];
            sf[qg][0] = *(const bf16x8*)&srow[quad * 8];
            sf[qg][1] = *(const bf16x8*)&srow[32 + quad * 8];
        }
#pragma unroll
        for (int ft = 0; ft < 4; ++ft) {
            bf16x8 g0 = *(const bf16x8*)&Gt[(ft * 16 + l16) * KS + quad * 8];
            bf16x8 g1 = *(const bf16x8*)&Gt[(ft * 16 + l16) * KS + 32 + quad * 8];
#pragma unroll
            for (int qg = 0; qg < 2; ++qg) {
                oacc[ft][qg] = __builtin_amdgcn_mfma_f32_16x16x32_bf16(g0, sf[qg][0], oacc[ft][qg], 0, 0, 0);
                oacc[ft][qg] = __builtin_amdgcn_mfma_f32_16x16x32_bf16(g1, sf[qg][1], oacc[ft][qg], 0, 0, 0);
            }
        }
    }

    // Epilogue: D row = f = ft*16+quad*4+r, col = q = q0+wave*32+qg*16+l16
#pragma unroll
    for (int ft = 0; ft < 4; ++ft)
#pragma unroll
        for (int qg = 0; qg < 2; ++qg)
#pragma unroll
            for (int r = 0; r < 4; ++r) {
                int f = ft * 16 + quad * 4 + r;
                int q = q0 + wave * 32 + qg * 16 + l16;
                unsafeAtomicAdd(&out[((size_t)t * F + f) * (size_t)N + q], oacc[ft][qg][r]);
            }
}

// ---------------------------------------------------------------------------
extern "C" void kernel_launch(void* const* d_in, const int* in_sizes, int n_in,
                              void* d_out, int out_size, void* d_ws, size_t ws_size,
                              hipStream_t stream) {
    const float* x1 = (const float*)d_in[0];
    const float* x2 = (const float*)d_in[1];
    const float* W1 = (const float*)d_in[2];
    const float* b1 = (const float*)d_in[3];
    const float* W2 = (const float*)d_in[4];
    const float* b2 = (const float*)d_in[5];
    const float* W3 = (const float*)d_in[6];
    const float* b3 = (const float*)d_in[7];
    float* out = (float*)d_out;

    __bf16* Qb = (__bf16*)d_ws;
    __bf16* Kb = Qb + (size_t)T * N * F;
    __bf16* Gw = Kb + (size_t)T * N * F;
    __bf16* Wb = Gw + (size_t)T * N * F;

    prep_w_kernel<<<dim3(3 * F * C / 256), dim3(256), 0, stream>>>(W1, W2, W3, Wb);
    proj_kernel<<<dim3(T * (N / 64)), dim3(256), 0, stream>>>(
        x1, x2, Wb, b1, b2, b3, Qb, Kb, Gw);
    zero_out_kernel<<<dim3(T * F * N / 4 / 256), dim3(256), 0, stream>>>(out);
    attn_kernel<<<dim3(T * 32 * KSPLIT), dim3(256), 0, stream>>>(Qb, Kb, Gw, out);
}

// Round 4
// 151.904 us; speedup vs baseline: 1.4231x; 1.0300x over previous
//
#include <hip/hip_runtime.h>
#include <hip/hip_bf16.h>

// Problem constants (B=1 folded out)
constexpr int T = 8;     // frames
constexpr int C = 128;   // input channels
constexpr int N = 4096;  // H*W positions
constexpr int F = 64;    // feature dim

typedef __bf16 bf16x8 __attribute__((ext_vector_type(8)));
typedef __bf16 bf16x4 __attribute__((ext_vector_type(4)));
typedef __bf16 bf16x2 __attribute__((ext_vector_type(2)));
typedef float  f32x4  __attribute__((ext_vector_type(4)));
typedef float  f32x16 __attribute__((ext_vector_type(16)));

// ---------------------------------------------------------------------------
// Kernel 0 (fused): zero d_out (attn accumulates with atomics) + convert
// W1/W2/W3 (fp32 [F][C]) to bf16 packed [3][F][C]. Grid = 2048 blocks covers
// the T*F*N/4 float4 zero-stores; first 24576 threads also convert W.
// ---------------------------------------------------------------------------
__global__ __launch_bounds__(256) void setup_kernel(
    const float* __restrict__ W1, const float* __restrict__ W2,
    const float* __restrict__ W3, __bf16* __restrict__ Wb,
    float* __restrict__ out)
{
    int i = blockIdx.x * 256 + threadIdx.x;
    ((f32x4*)out)[i] = (f32x4){0.f, 0.f, 0.f, 0.f};
    if (i < 3 * F * C) {
        int p = i >> 13, r = i & 8191;
        const float* W = (p == 0) ? W1 : (p == 1) ? W2 : W3;
        Wb[i] = (__bf16)W[r];
    }
}

// ---------------------------------------------------------------------------
// Kernel 1: projections (verified in round 2, unchanged).
//   Q,K: D[m=f][n'=n] = W · X^T -> [n][F], b64 stores over f
//   G:   D[m=n][n'=f] = X^T · W3 -> [f][N], b64 stores over n
// ---------------------------------------------------------------------------
__global__ __launch_bounds__(256) void proj_kernel(
    const float* __restrict__ x1, const float* __restrict__ x2,
    const __bf16* __restrict__ Wb,
    const float* __restrict__ b1, const float* __restrict__ b2,
    const float* __restrict__ b3,
    __bf16* __restrict__ Qb, __bf16* __restrict__ Kb, __bf16* __restrict__ Gw)
{
    const int t  = blockIdx.x >> 6;
    const int nb = blockIdx.x & 63;
    const int n0 = nb * 64;

    constexpr int XS = 136;           // 272B rows (16B aligned)
    __shared__ __bf16 Xt1[64 * XS];   // X1^T tile: [n_local][c]
    __shared__ __bf16 Xt2[64 * XS];

    const int tid = threadIdx.x;
    const int ng  = tid & 15;         // n-block: n = ng*4 + j
    const int cgi = tid >> 4;         // c-group: c = cgi*4 (+64 per pass)

#pragma unroll
    for (int pass = 0; pass < 2; ++pass) {
        const int c0 = cgi * 4 + pass * 64;
        const size_t base = ((size_t)t * C + c0) * (size_t)N + n0 + ng * 4;
        f32x4 v1[4], v2[4];
#pragma unroll
        for (int i = 0; i < 4; ++i) {
            v1[i] = *(const f32x4*)&x1[base + (size_t)i * N];
            v2[i] = *(const f32x4*)&x2[base + (size_t)i * N];
        }
#pragma unroll
        for (int j = 0; j < 4; ++j) {
            bf16x4 o1, o2;
#pragma unroll
            for (int i = 0; i < 4; ++i) {
                o1[i] = (__bf16)v1[i][j];
                o2[i] = (__bf16)v2[i][j];
            }
            *(bf16x4*)&Xt1[(ng * 4 + j) * XS + c0] = o1;
            *(bf16x4*)&Xt2[(ng * 4 + j) * XS + c0] = o2;
        }
    }
    __syncthreads();

    const int wave = tid >> 6, lane = tid & 63;
    const int quad = lane >> 4, l16 = lane & 15;

    bf16x8 a1[4], a2[4];
#pragma unroll
    for (int cc = 0; cc < 4; ++cc) {
        a1[cc] = *(const bf16x8*)&Xt1[(wave * 16 + l16) * XS + cc * 32 + quad * 8];
        a2[cc] = *(const bf16x8*)&Xt2[(wave * 16 + l16) * XS + cc * 32 + quad * 8];
    }

    // ---- Q and K: D[m=f][n'=n] = W · X^T ----
#pragma unroll
    for (int p = 0; p < 2; ++p) {
        const __bf16* W    = Wb + (size_t)p * F * C;
        const float*  bias = p ? b2 : b1;
        __bf16*       O    = p ? Kb : Qb;

        f32x4 acc[4];
#pragma unroll
        for (int ft = 0; ft < 4; ++ft) acc[ft] = (f32x4){0.f, 0.f, 0.f, 0.f};
#pragma unroll
        for (int cc = 0; cc < 4; ++cc) {
#pragma unroll
            for (int ft = 0; ft < 4; ++ft) {
                bf16x8 wf = *(const bf16x8*)&W[(ft * 16 + l16) * C + cc * 32 + quad * 8];
                bf16x8 xf = p ? a2[cc] : a1[cc];
                acc[ft] = __builtin_amdgcn_mfma_f32_16x16x32_bf16(wf, xf, acc[ft], 0, 0, 0);
            }
        }
        const int n = n0 + wave * 16 + l16;
#pragma unroll
        for (int ft = 0; ft < 4; ++ft) {
            const int f0 = ft * 16 + quad * 4;
            f32x4 bv = *(const f32x4*)&bias[f0];
            bf16x4 o;
#pragma unroll
            for (int r = 0; r < 4; ++r) o[r] = (__bf16)(acc[ft][r] + bv[r]);
            *(bf16x4*)&O[((size_t)t * N + n) * F + f0] = o;
        }
    }

    // ---- G: D[m=n][n'=f] = X^T · W3 ----
    {
        const __bf16* W3b = Wb + (size_t)2 * F * C;
        f32x4 acc[4];
#pragma unroll
        for (int ft = 0; ft < 4; ++ft) acc[ft] = (f32x4){0.f, 0.f, 0.f, 0.f};
#pragma unroll
        for (int cc = 0; cc < 4; ++cc) {
#pragma unroll
            for (int ft = 0; ft < 4; ++ft) {
                bf16x8 wf = *(const bf16x8*)&W3b[(ft * 16 + l16) * C + cc * 32 + quad * 8];
                acc[ft] = __builtin_amdgcn_mfma_f32_16x16x32_bf16(a1[cc], wf, acc[ft], 0, 0, 0);
            }
        }
        const int nr0 = n0 + wave * 16 + quad * 4;
#pragma unroll
        for (int ft = 0; ft < 4; ++ft) {
            const int f = ft * 16 + l16;
            const float bv = b3[f];
            bf16x4 o;
#pragma unroll
            for (int r = 0; r < 4; ++r) o[r] = (__bf16)(acc[ft][r] + bv);
            *(bf16x4*)&Gw[((size_t)t * F + f) * (size_t)N + nr0] = o;
        }
    }
}

// ---------------------------------------------------------------------------
// Kernel 2: O[t][f][q] += sum_key relu(Q[q]·K[key]) * G[key][f]
//
// v3: round-2 LDS-staged structure + 32x32x16 MFMA + in-register S path.
// Block 256 = 4 waves; each wave owns 32 q (q = q0 + wave*32 + m32) and all
// 64 keys of the tile. Sᵀ = relu(K·Qᵀ) computed per 32-key block: D gives
// lane(hi,m32) -> S[key=(r&3)+8*(r>>2)+4*hi][q=m32]. relu+pack to bf16 pairs,
// then v_permlane32_swap (P0↔P2, P1↔P3, P4↔P6, P5↔P7) assembles the PV
// B-fragments directly (layout verified end-to-end in round 1). No Sb LDS
// buffer: LDS ops/wave-iter drop 24r+12w -> 16r+4w, LDS 36864 -> 18432 B.
// ---------------------------------------------------------------------------
constexpr int KSPLIT = 4;

__global__ __launch_bounds__(256) void attn_kernel(
    const __bf16* __restrict__ Qb, const __bf16* __restrict__ Kb,
    const __bf16* __restrict__ Gw, float* __restrict__ out)
{
    const int ks = blockIdx.x & (KSPLIT - 1);
    const int qb = (blockIdx.x / KSPLIT) & 31;   // N/128 = 32 q-blocks
    const int t  = blockIdx.x / (KSPLIT * 32);
    const int q0 = qb * 128;

    constexpr int KS = 72;              // bf16 stride (144B rows, 16B aligned)
    __shared__ __bf16 Kt[64 * KS];      // K tile [key][f]
    __shared__ __bf16 Gt[64 * KS];      // G tile [f][key]

    const int tid = threadIdx.x, wave = tid >> 6, lane = tid & 63;
    const int m32 = lane & 31, hi = lane >> 5;

    // Q B-frags (32x32x16): lane holds Q[q = q0+wave*32+m32][f = fc*16+hi*8+j]
    bf16x8 qf[4];
    {
        const __bf16* qrow = &Qb[((size_t)t * N + q0 + wave * 32 + m32) * F + hi * 8];
#pragma unroll
        for (int fc = 0; fc < 4; ++fc)
            qf[fc] = *(const bf16x8*)(qrow + fc * 16);
    }

    f32x16 oacc[2];   // [f-tile]; D: col=q=m32, row=f=ft*32+(r&3)+8*(r>>2)+4*hi
#pragma unroll
    for (int ft = 0; ft < 2; ++ft)
#pragma unroll
        for (int r = 0; r < 16; ++r) oacc[ft][r] = 0.f;

    const int kb_lo = ks * (N / 64 / KSPLIT);
    const int kb_hi = kb_lo + (N / 64 / KSPLIT);

    // staging unit: u in {tid, tid+256}; r8 = u>>3 (row), c8 = (u&7)*8 (col)
    const int r8a = tid >> 3,          c8a = (tid & 7) * 8;
    const int r8b = (tid + 256) >> 3,  c8b = c8a;

    // prefetch tile kb_lo into registers
    bf16x8 kv0, kv1, gv0, gv1;
    {
        const int k0 = kb_lo * 64;
        kv0 = *(const bf16x8*)&Kb[((size_t)t * N + k0 + r8a) * F + c8a];
        kv1 = *(const bf16x8*)&Kb[((size_t)t * N + k0 + r8b) * F + c8b];
        gv0 = *(const bf16x8*)&Gw[((size_t)t * F + r8a) * (size_t)N + k0 + c8a];
        gv1 = *(const bf16x8*)&Gw[((size_t)t * F + r8b) * (size_t)N + k0 + c8b];
    }

    for (int kb = kb_lo; kb < kb_hi; ++kb) {
        __syncthreads();   // previous tile's LDS reads done
        *(bf16x8*)&Kt[r8a * KS + c8a] = kv0;
        *(bf16x8*)&Kt[r8b * KS + c8b] = kv1;
        *(bf16x8*)&Gt[r8a * KS + c8a] = gv0;
        *(bf16x8*)&Gt[r8b * KS + c8b] = gv1;
        __syncthreads();

        if (kb + 1 < kb_hi) {   // prefetch next tile (overlaps with compute)
            const int k0 = (kb + 1) * 64;
            kv0 = *(const bf16x8*)&Kb[((size_t)t * N + k0 + r8a) * F + c8a];
            kv1 = *(const bf16x8*)&Kb[((size_t)t * N + k0 + r8b) * F + c8b];
            gv0 = *(const bf16x8*)&Gw[((size_t)t * F + r8a) * (size_t)N + k0 + c8a];
            gv1 = *(const bf16x8*)&Gw[((size_t)t * F + r8b) * (size_t)N + k0 + c8b];
        }

        // ---- S + pack: per 32-key block, Sᵀ stays in registers ----
        bf16x8 ps[4];   // PV B-frags: ps[kt*2+kc] = keys kt*32+kc*16+hi*8+(0..7)
#pragma unroll
        for (int kt = 0; kt < 2; ++kt) {
            f32x16 s;
#pragma unroll
            for (int r = 0; r < 16; ++r) s[r] = 0.f;
#pragma unroll
            for (int fc = 0; fc < 4; ++fc) {
                bf16x8 kf = *(const bf16x8*)&Kt[(kt * 32 + m32) * KS + fc * 16 + hi * 8];
                s = __builtin_amdgcn_mfma_f32_32x32x16_bf16(kf, qf[fc], s, 0, 0, 0);
            }
            unsigned P[8];
#pragma unroll
            for (int m = 0; m < 8; ++m) {
                union { bf16x2 h; unsigned u; } pk;
                pk.h[0] = (__bf16)fmaxf(s[2 * m], 0.f);
                pk.h[1] = (__bf16)fmaxf(s[2 * m + 1], 0.f);
                P[m] = pk.u;
            }
            asm("v_permlane32_swap_b32 %0, %1" : "+v"(P[0]), "+v"(P[2]));
            asm("v_permlane32_swap_b32 %0, %1" : "+v"(P[1]), "+v"(P[3]));
            asm("v_permlane32_swap_b32 %0, %1" : "+v"(P[4]), "+v"(P[6]));
            asm("v_permlane32_swap_b32 %0, %1" : "+v"(P[5]), "+v"(P[7]));
            union { unsigned u[4]; bf16x8 v; } lo, hiu;
            lo.u[0]  = P[0]; lo.u[1]  = P[1]; lo.u[2]  = P[2]; lo.u[3]  = P[3];
            hiu.u[0] = P[4]; hiu.u[1] = P[5]; hiu.u[2] = P[6]; hiu.u[3] = P[7];
            ps[kt * 2]     = lo.v;
            ps[kt * 2 + 1] = hiu.v;
        }

        // ---- PV: Oᵀ[f][q]; A = Gt rows (f), k-dim = keys ----
#pragma unroll
        for (int ft = 0; ft < 2; ++ft)
#pragma unroll
            for (int kt = 0; kt < 2; ++kt)
#pragma unroll
                for (int kc = 0; kc < 2; ++kc) {
                    bf16x8 gfr = *(const bf16x8*)&Gt[(ft * 32 + m32) * KS +
                                                     kt * 32 + kc * 16 + hi * 8];
                    oacc[ft] = __builtin_amdgcn_mfma_f32_32x32x16_bf16(
                        gfr, ps[kt * 2 + kc], oacc[ft], 0, 0, 0);
                }
    }

    // Epilogue: f = ft*32+(r&3)+8*(r>>2)+4*hi, q = q0+wave*32+m32
    const int q = q0 + wave * 32 + m32;
#pragma unroll
    for (int ft = 0; ft < 2; ++ft)
#pragma unroll
        for (int r = 0; r < 16; ++r) {
            int f = ft * 32 + (r & 3) + 8 * (r >> 2) + 4 * hi;
            unsafeAtomicAdd(&out[((size_t)t * F + f) * (size_t)N + q], oacc[ft][r]);
        }
}

// ---------------------------------------------------------------------------
extern "C" void kernel_launch(void* const* d_in, const int* in_sizes, int n_in,
                              void* d_out, int out_size, void* d_ws, size_t ws_size,
                              hipStream_t stream) {
    const float* x1 = (const float*)d_in[0];
    const float* x2 = (const float*)d_in[1];
    const float* W1 = (const float*)d_in[2];
    const float* b1 = (const float*)d_in[3];
    const float* W2 = (const float*)d_in[4];
    const float* b2 = (const float*)d_in[5];
    const float* W3 = (const float*)d_in[6];
    const float* b3 = (const float*)d_in[7];
    float* out = (float*)d_out;

    __bf16* Qb = (__bf16*)d_ws;
    __bf16* Kb = Qb + (size_t)T * N * F;
    __bf16* Gw = Kb + (size_t)T * N * F;
    __bf16* Wb = Gw + (size_t)T * N * F;

    setup_kernel<<<dim3(T * F * N / 4 / 256), dim3(256), 0, stream>>>(
        W1, W2, W3, Wb, out);
    proj_kernel<<<dim3(T * (N / 64)), dim3(256), 0, stream>>>(
        x1, x2, Wb, b1, b2, b3, Qb, Kb, Gw);
    attn_kernel<<<dim3(T * 32 * KSPLIT), dim3(256), 0, stream>>>(Qb, Kb, Gw, out);
}